// Round 4
// baseline (541.000 us; speedup 1.0000x reference)
//
#include <hip/hip_runtime.h>
#include <stdint.h>
#include <algorithm>

// Sparse conv encoder on MI355X. R9: deep-pipeline mconv (BK=32, 3 LDS bufs,
// depth-2 prefetch, counted vmcnt(4)) + occupancy push (LDS 48KB -> 3
// blocks/CU target, __launch_bounds__(512,6)).
// R8 analysis: mconv still latency-bound (depth-1 cover ~150cy vs 200-600cy
// gather latency; 2 blocks/CU). R9 gives each load ~2 step-times of cover and
// up to 24 waves/CU. Bank spread for 64B rows: chunk ^= (row>>1)&3 (2-way =
// free), applied on gload SOURCE + ds_read (both-sides rule). fp32-input
// fallback dropped: ws (550MB) >> full-tier need (~140MB); d0/d1 dual-write
// bf16 copies so every mconv input is bf16.
// Kept (verified): flattened-K gather GEMM, gload_lds 16B, reg-precomputed
// gather offsets (zero-page folded), XCD chunk swizzle, setprio, consolidated
// prep dispatches (9 total).
// Predict: 487 -> ~390-420us; mconv LDS 49KB, VGPR ~85, Occ 40-65%.

#define DI __device__ __forceinline__

typedef __attribute__((ext_vector_type(8))) short bf16x8;
typedef __attribute__((ext_vector_type(4))) float f32x4;

DI uint16_t f2bf(float x){
  union{float f;uint32_t i;}v; v.f=x;
  uint32_t r = v.i + 0x7fffu + ((v.i>>16)&1u);
  return (uint16_t)(r>>16);
}
DI uint32_t pack2(float a, float b){
  return (uint32_t)f2bf(a) | ((uint32_t)f2bf(b) << 16);
}
DI void gload16(const void* g, void* l){
  __builtin_amdgcn_global_load_lds(
      (const __attribute__((address_space(1))) void*)g,
      (__attribute__((address_space(3))) void*)l, 16, 0, 0);
}

__global__ __launch_bounds__(256) void diag_kernel(float* __restrict__ out, long n, float c){
  long i = (long)blockIdx.x*256 + threadIdx.x;
  if (i < n) out[i] = c;
}

// fill all tables with -1 + zero the 256B zero page, one dispatch
__global__ __launch_bounds__(256) void init_all_kernel(
    int* __restrict__ tab, long ntab, float* __restrict__ zp){
  long i = (long)blockIdx.x*256 + threadIdx.x;
  if (i < ntab) tab[i] = -1;
  if (blockIdx.x == 0 && threadIdx.x < 64) zp[threadIdx.x] = 0.f;
}

struct BuildArgs {
  const int* im[6];
  const int* om[6];
  int   M[6];
  int   nin[6];
  int   nout[6];
  long  toff[6];   // int offsets into table base
};

// all 6 layers' inverse tables, one dispatch (z = layer, y = offset k)
__global__ __launch_bounds__(256) void build_all_kernel(
    BuildArgs a, int* __restrict__ tb){
  const int L = blockIdx.z, k = blockIdx.y;
  const int M = a.M[L];
  long t = (long)blockIdx.x*256 + threadIdx.x;
  if (t >= M) return;
  int ii = a.im[L][(long)k*M + t];
  int oo = a.om[L][(long)k*M + t];
  if (ii >= 0 && ii < a.nin[L] && oo >= 0 && oo < a.nout[L])
    tb[a.toff[L] + (long)k*a.nout[L] + oo] = ii;
}

// all 5 weight transposes (9,cin,128) fp32 -> (9,128,cin) bf16, one dispatch.
__global__ __launch_bounds__(256) void prep_all_kernel(
    const float* __restrict__ w0, const float* __restrict__ w1,
    const float* __restrict__ w2, const float* __restrict__ w3,
    const float* __restrict__ w4, uint16_t* __restrict__ wb, long total){
  const long wt64 = 9L*128*64, wt128 = 9L*128*128;
  long idx = (long)blockIdx.x*256 + threadIdx.x;
  if (idx >= total) return;
  int L; long r; int cin;
  if (idx < wt64){ L = 0; r = idx; cin = 64; }
  else { long j = idx - wt64; L = 1 + (int)(j / wt128); r = j % wt128; cin = 128; }
  const float* w = (L==0) ? w0 : (L==1) ? w1 : (L==2) ? w2 : (L==3) ? w3 : w4;
  int k = (int)(r / (128*cin));
  int rem = (int)(r % (128*cin));
  int cout = rem / cin, ci = rem % cin;
  wb[idx] = f2bf(w[((long)k*cin + ci)*128 + cout]);
}

// c0 (1->64 ch) via table: thread = row; 9 table reads + 9 cached gathers + FMA.
__global__ __launch_bounds__(256) void c0_tab_kernel(
    const float* __restrict__ feats, const float* __restrict__ w,
    const float* __restrict__ bias, const int* __restrict__ tab,
    uint16_t* __restrict__ out, int n_out){
  __shared__ float w_s[576];
  __shared__ float b_s[64];
  const int tid = threadIdx.x;
  for (int i = tid; i < 576; i += 256) w_s[i] = w[i];
  if (tid < 64) b_s[tid] = bias[tid];
  __syncthreads();
  long r = (long)blockIdx.x*256 + tid;
  if (r >= n_out) return;
  float f[9];
  #pragma unroll
  for (int k = 0; k < 9; k++){
    int gi = tab[(long)k*n_out + r];
    f[k] = (gi >= 0) ? feats[gi] : 0.f;
  }
  uint16_t* dst = out + r*64;
  #pragma unroll
  for (int c0 = 0; c0 < 64; c0 += 16){
    float a[16];
    #pragma unroll
    for (int j = 0; j < 16; j++) a[j] = b_s[c0+j];
    #pragma unroll
    for (int k = 0; k < 9; k++){
      float fk = f[k];
      #pragma unroll
      for (int j = 0; j < 16; j++) a[j] += fk * w_s[k*64 + c0 + j];
    }
    uint4 o0, o1;
    o0.x = pack2(a[0],a[1]);   o0.y = pack2(a[2],a[3]);
    o0.z = pack2(a[4],a[5]);   o0.w = pack2(a[6],a[7]);
    o1.x = pack2(a[8],a[9]);   o1.y = pack2(a[10],a[11]);
    o1.z = pack2(a[12],a[13]); o1.w = pack2(a[14],a[15]);
    *(uint4*)(dst + c0)     = o0;
    *(uint4*)(dst + c0 + 8) = o1;
  }
}

// Flattened-K gathered GEMM, BM=128 x BN=128, BK=32, 512 thr (8 waves 4x2,
// wave tile 32x64). 3 LDS buffers, depth-2 prefetch, counted vmcnt.
// Input is always bf16 [n_in][CIN] inside ws at in_off.
// OUTMODE: 0 = fp32 only; 1 = bf16 only; 2 = both.
template<int CIN, int OUTMODE, bool RELU>
__global__ __launch_bounds__(512,6) void mconv3_kernel(
    const char* __restrict__ ws_base, long in_off, long wtb_off, long zp_off,
    const float* __restrict__ bias, const int* __restrict__ tab,
    float* __restrict__ outf, uint16_t* __restrict__ outb, int n_out){
  constexpr int NS = 9*CIN/32;                       // K-steps of 32
  __shared__ __align__(16) uint16_t ab[3][128*32];   // A: 128 rows x 32 (8KB)
  __shared__ __align__(16) uint16_t bb[3][128*32];   // B: 128 couts x 32 (8KB)

  const int tid = threadIdx.x;
  // bijective XCD-chunked swizzle (m204) for gather L2 locality
  const int nwg = gridDim.x, orig = blockIdx.x;
  const int q = nwg >> 3, rr = nwg & 7, xcd = orig & 7, pos = orig >> 3;
  const int wg = (xcd < rr ? xcd*(q+1) : rr*(q+1) + (xcd-rr)*q) + pos;
  const long rb = (long)wg * 128;

  // staging mapping: one 16B gload per thread per tile; row r0 = tid>>2,
  // chunk sg = tid&3; logical chunk lsg = sg ^ ((r0>>1)&3) (2-way bank = free)
  const int r0 = tid >> 2, sg = tid & 3;
  const int lsg = sg ^ ((r0 >> 1) & 3);

  // A gather offsets: ws-relative uint32, zero-page select folded, per kk.
  uint32_t offA[9];
  #pragma unroll
  for (int kk = 0; kk < 9; ++kk){
    long row = rb + r0;
    int gi = (row < (long)n_out) ? tab[(long)kk*n_out + row] : -1;
    offA[kk] = (gi >= 0) ? (uint32_t)(in_off + (long)gi*(CIN*2) + lsg*16)
                         : (uint32_t)(zp_off + lsg*16);
  }
  const uint32_t offB0 = (uint32_t)(wtb_off + ((long)r0*CIN + lsg*8)*2);

  const int lane = tid & 63;
  const int wv = tid >> 6;
  const int wr = (wv >> 1) << 5;    // 4 row-waves x 32
  const int wc = (wv & 1) << 6;     // 2 col-waves x 64
  const int l16 = lane & 15, quad = lane >> 4;
  // read-side chunk xor: row = (0 mod 16) + l16 -> ((row>>1)&3) == ((l16>>1)&3)
  const int xsw = (quad ^ ((l16 >> 1) & 3)) << 3;

  // bias preload (prologue VMEM is fully drained by the first vmcnt(4): at
  // iter0 wait, 3 oldest ops drain = bias + stage(0)'s position-invariant set)
  float bv[4];
  #pragma unroll
  for (int ct = 0; ct < 4; ++ct) bv[ct] = bias[wc + (ct<<4) + l16];

  f32x4 acc[2][4];
  #pragma unroll
  for (int i = 0; i < 2; i++)
    #pragma unroll
    for (int j = 0; j < 4; j++)
      acc[i][j] = (f32x4){0.f,0.f,0.f,0.f};

  auto stage = [&](int t, int nb){
    const int kk = t / (CIN/32), ch = t % (CIN/32);
    gload16(ws_base + offA[kk] + ch*64, &ab[nb][tid*8]);
    gload16(ws_base + offB0 + (uint32_t)((long)kk*128*CIN*2) + ch*64,
            &bb[nb][tid*8]);
  };
  auto compute = [&](int nb){
    const uint16_t* A  = &ab[nb][0];
    const uint16_t* Bm = &bb[nb][0];
    __builtin_amdgcn_s_setprio(1);
    bf16x8 af[2], bfr[4];
    #pragma unroll
    for (int u = 0; u < 2; ++u)
      af[u]  = *(const bf16x8*)&A [((wr + (u<<4) + l16) << 5) + xsw];
    #pragma unroll
    for (int u = 0; u < 4; ++u)
      bfr[u] = *(const bf16x8*)&Bm[((wc + (u<<4) + l16) << 5) + xsw];
    #pragma unroll
    for (int rt = 0; rt < 2; ++rt)
      #pragma unroll
      for (int ct = 0; ct < 4; ++ct)
        acc[rt][ct] = __builtin_amdgcn_mfma_f32_16x16x32_bf16(
            af[rt], bfr[ct], acc[rt][ct], 0, 0, 0);
    __builtin_amdgcn_s_setprio(0);
  };

  // depth-2 pipeline: buffers t%3; stage(t+2) issued while t computes.
  // Steady state: 6 loads outstanding; vmcnt(4) waits only stage(t)'s 2.
  stage(0, 0);
  stage(1, 1);
  #pragma unroll
  for (int t = 0; t < NS; ++t){
    if (t + 2 < NS){
      stage(t+2, (t+2)%3);
      asm volatile("s_waitcnt vmcnt(4)" ::: "memory");
    } else if (t + 1 < NS){
      asm volatile("s_waitcnt vmcnt(2)" ::: "memory");
    } else {
      asm volatile("s_waitcnt vmcnt(0)" ::: "memory");
    }
    __builtin_amdgcn_sched_barrier(0);
    __builtin_amdgcn_s_barrier();     // all waves' stage(t) slices landed
    compute(t%3);
    if (t + 1 < NS)
      __builtin_amdgcn_s_barrier();   // WAR: buf (t+1)%3... (t-1)%3 reusable
  }

  // C/D mapping (verified): col = l16, row = quad*4 + r
  #pragma unroll
  for (int ct = 0; ct < 4; ++ct){
    const int cout = wc + (ct<<4) + l16;
    #pragma unroll
    for (int rt = 0; rt < 2; ++rt){
      #pragma unroll
      for (int r = 0; r < 4; ++r){
        long row = rb + wr + (rt<<4) + (quad<<2) + r;
        if (row < (long)n_out){
          float v = acc[rt][ct][r] + bv[ct];
          if (RELU) v = v > 0.f ? v : 0.f;
          if constexpr (OUTMODE == 0 || OUTMODE == 2) outf[row*128 + cout] = v;
          if constexpr (OUTMODE == 1 || OUTMODE == 2) outb[row*128 + cout] = f2bf(v);
        }
      }
    }
  }
}

static inline long cdivl(long a, long b){ return (a + b - 1) / b; }

extern "C" void kernel_launch(void* const* d_in, const int* in_sizes, int n_in_args,
                              void* d_out, int out_size, void* d_ws, size_t ws_size,
                              hipStream_t stream) {
  const float* feats = (const float*)d_in[0];
  const float* w_c0 = (const float*)d_in[1];
  const float* b_c0 = (const float*)d_in[2];
  const int* in_c0  = (const int*)d_in[3];
  const int* out_c0 = (const int*)d_in[4];
  const float* w_d0 = (const float*)d_in[5];
  const float* b_d0 = (const float*)d_in[6];
  const int* in_d0  = (const int*)d_in[7];
  const int* out_d0 = (const int*)d_in[8];
  const float* w_c1 = (const float*)d_in[9];
  const float* b_c1 = (const float*)d_in[10];
  const int* in_c1  = (const int*)d_in[11];
  const int* out_c1 = (const int*)d_in[12];
  const float* w_d1 = (const float*)d_in[13];
  const float* b_d1 = (const float*)d_in[14];
  const int* in_d1  = (const int*)d_in[15];
  const int* out_d1 = (const int*)d_in[16];
  const float* w_c2 = (const float*)d_in[17];
  const float* b_c2 = (const float*)d_in[18];
  const int* in_c2  = (const int*)d_in[19];
  const int* out_c2 = (const int*)d_in[20];
  const float* w_d2 = (const float*)d_in[21];
  const float* b_d2 = (const float*)d_in[22];
  const int* in_d2  = (const int*)d_in[23];
  const int* out_d2 = (const int*)d_in[24];

  const int n0   = in_sizes[0];
  const int M_c0 = in_sizes[3]  / 9;
  const int M_d0 = in_sizes[7]  / 9;
  const int M_c1 = in_sizes[11] / 9;
  const int M_d1 = in_sizes[15] / 9;
  const int M_c2 = in_sizes[19] / 9;
  const int M_d2 = in_sizes[23] / 9;
  const int n1   = M_c1;
  const int n2   = M_c2;
  const int n3   = out_size/128 - n1 - n2;

  bool sane = n0 > 0 && out_size % 128 == 0 &&
              M_c0 > 0 && M_d0 > 0 && M_d1 > 0 && M_d2 > 0 &&
              n1 > 0 && n2 > 0 && n3 > 0;

  long maxElems = (long)n0*64;
  if ((long)n1*128 > maxElems) maxElems = (long)n1*128;
  if ((long)n2*128 > maxElems) maxElems = (long)n2*128;
  long fbytes = (maxElems*2 + 255)/256*256;
  long ntab   = sane ? 9L*((long)n0 + 2L*n1 + 2L*n2 + n3) : 0;
  long tbytes = (ntab*4 + 255)/256*256;
  long wt64  = 9L*128*64, wt128 = 9L*128*128;
  long wbytes = ((wt64 + 4*wt128)*2 + 255)/256*256;
  long zbytes = 256;
  long b1bytes = sane ? ((long)n2*128*2 + 255)/256*256 : 0;
  long b0bytes = sane ? ((long)n1*128*2 + 255)/256*256 : 0;
  long need_full = fbytes + tbytes + wbytes + zbytes + 256 + b1bytes + b0bytes;

  if (!sane || ws_size < (size_t)need_full){
    float C = (float)(16 + (int)std::min<size_t>(ws_size >> 20, (size_t)100000));
    if (!sane) C *= 1099511627776.0f;
    diag_kernel<<<cdivl(out_size,256),256,0,stream>>>((float*)d_out, out_size, C);
    return;
  }

  // ws: [ fbuf | tables x6 | wtb x5 | zero page | bf1 | bf0 ]
  uint16_t* fbuf = (uint16_t*)d_ws;
  long tab_off    = fbytes;
  long wtb_off    = fbytes + tbytes;
  long zp_off     = fbytes + tbytes + wbytes;
  long bf1_off    = zp_off + zbytes + 256;
  long bf0_off    = bf1_off + b1bytes;
  const char* wsb = (const char*)d_ws;
  int* tb        = (int*)((char*)d_ws + tab_off);
  float* zp_p    = (float*)((char*)d_ws + zp_off);
  uint16_t* bf1  = (uint16_t*)((char*)d_ws + bf1_off);
  uint16_t* bf0  = (uint16_t*)((char*)d_ws + bf0_off);

  // table int offsets (contiguous, order: c0 d0 c1 d1 c2 d2)
  long t_c0 = 0;
  long t_d0 = t_c0 + 9L*n0;
  long t_c1 = t_d0 + 9L*n1;
  long t_d1 = t_c1 + 9L*n1;
  long t_c2 = t_d1 + 9L*n2;
  long t_d2 = t_c2 + 9L*n2;

  float* out2 = (float*)d_out;
  float* out1 = out2 + (long)n3*128;
  float* out0 = out1 + (long)n2*128;

  // 1) init all tables + zero page
  init_all_kernel<<<cdivl(ntab,256),256,0,stream>>>(tb, ntab, zp_p);

  // 2) build all 6 tables
  BuildArgs ba;
  ba.im[0]=in_c0;  ba.om[0]=out_c0; ba.M[0]=M_c0; ba.nin[0]=n0; ba.nout[0]=n0; ba.toff[0]=t_c0;
  ba.im[1]=in_d0;  ba.om[1]=out_d0; ba.M[1]=M_d0; ba.nin[1]=n0; ba.nout[1]=n1; ba.toff[1]=t_d0;
  ba.im[2]=in_c1;  ba.om[2]=out_c1; ba.M[2]=M_c1; ba.nin[2]=n1; ba.nout[2]=n1; ba.toff[2]=t_c1;
  ba.im[3]=in_d1;  ba.om[3]=out_d1; ba.M[3]=M_d1; ba.nin[3]=n1; ba.nout[3]=n2; ba.toff[3]=t_d1;
  ba.im[4]=in_c2;  ba.om[4]=out_c2; ba.M[4]=M_c2; ba.nin[4]=n2; ba.nout[4]=n2; ba.toff[4]=t_c2;
  ba.im[5]=in_d2;  ba.om[5]=out_d2; ba.M[5]=M_d2; ba.nin[5]=n2; ba.nout[5]=n3; ba.toff[5]=t_d2;
  long maxM = M_c0;
  for (int i = 0; i < 6; ++i) if (ba.M[i] > maxM) maxM = ba.M[i];
  dim3 bg((unsigned)cdivl(maxM,256), 9, 6);
  build_all_kernel<<<bg,256,0,stream>>>(ba, tb);

  // 3) all weight transposes
  long wtotal = wt64 + 4*wt128;
  prep_all_kernel<<<cdivl(wtotal,256),256,0,stream>>>(
      w_d0, w_c1, w_d1, w_c2, w_d2,
      (uint16_t*)((char*)d_ws + wtb_off), wtotal);

  // 4) c0: feats fp32 -> fbuf(x) bf16 [n0][64]
  c0_tab_kernel<<<cdivl(n0,256),256,0,stream>>>(feats, w_c0, b_c0, tb + t_c0, fbuf, n0);

  // 5) d0: x bf16 -> out0 fp32 + bf0 bf16, relu
  mconv3_kernel<64,2,true><<<cdivl(n1,128),512,0,stream>>>(
      wsb, 0L, wtb_off, zp_off, b_d0, tb + t_d0, out0, bf0, n1);

  // 6) c1: bf0 bf16 -> fbuf(y) bf16
  mconv3_kernel<128,1,false><<<cdivl(n1,128),512,0,stream>>>(
      wsb, bf0_off, wtb_off + wt64*2, zp_off, b_c1, tb + t_c1, nullptr, fbuf, n1);

  // 7) d1: y bf16 -> out1 fp32 + bf1 bf16, relu
  mconv3_kernel<128,2,true><<<cdivl(n2,128),512,0,stream>>>(
      wsb, 0L, wtb_off + (wt64 + wt128)*2, zp_off, b_d1, tb + t_d1, out1, bf1, n2);

  // 8) c2: bf1 bf16 -> fbuf(z) bf16
  mconv3_kernel<128,1,false><<<cdivl(n2,128),512,0,stream>>>(
      wsb, bf1_off, wtb_off + (wt64 + 2*wt128)*2, zp_off, b_c2, tb + t_c2, nullptr, fbuf, n2);

  // 9) d2: z bf16 -> out2 fp32
  mconv3_kernel<128,0,false><<<cdivl(n3,128),512,0,stream>>>(
      wsb, 0L, wtb_off + (wt64 + 3*wt128)*2, zp_off, b_d2, tb + t_d2, out2, nullptr, n3);
}

// Round 5
// 491.002 us; speedup vs baseline: 1.1018x; 1.1018x over previous
//
#include <hip/hip_runtime.h>
#include <stdint.h>
#include <algorithm>

// Sparse conv encoder on MI355X. R10: revert R9's BK=32 (barrier-bound, +54us)
// back to R8's BK=64 structure, then add ASYMMETRIC prefetch depth:
//   A (gather, 400-700cy L3 latency): 3 buffers, staged 2 steps ahead
//   B (weights, L2-hot ~200cy):       2 buffers, staged 1 step ahead
// LDS = 3*16+2*16 = exactly 80KB -> keeps 2 blocks/CU (symmetric depth-2
// would need 96KB -> 1 block/CU). Same barrier count as R8; vmcnt(4) in
// steady state leaves exactly {A(t+2),B(t+1)} outstanding, so A(t) gets two
// compute+barrier phases (~700cy) of cover vs one (~310cy) in R8.
// Epilogue: vmcnt(2) at t=NS-2, vmcnt(0) at t=NS-1.
// Kept (verified): flattened-K gather GEMM, gload_lds 16B, source-side XOR
// seg swizzle (0 bank conflicts), reg-precomputed gather offsets w/ zero-page
// fold, XCD chunk swizzle, setprio, 9-dispatch consolidated prep.
// Predict: 541 -> ~430-455us; mconv LDS 81920, VGPR ~88, conflicts 0.

#define DI __device__ __forceinline__

typedef __attribute__((ext_vector_type(8))) short bf16x8;
typedef __attribute__((ext_vector_type(4))) float f32x4;

DI uint16_t f2bf(float x){
  union{float f;uint32_t i;}v; v.f=x;
  uint32_t r = v.i + 0x7fffu + ((v.i>>16)&1u);
  return (uint16_t)(r>>16);
}
DI uint32_t pack2(float a, float b){
  return (uint32_t)f2bf(a) | ((uint32_t)f2bf(b) << 16);
}
DI void gload16(const void* g, void* l){
  __builtin_amdgcn_global_load_lds(
      (const __attribute__((address_space(1))) void*)g,
      (__attribute__((address_space(3))) void*)l, 16, 0, 0);
}

__global__ __launch_bounds__(256) void diag_kernel(float* __restrict__ out, long n, float c){
  long i = (long)blockIdx.x*256 + threadIdx.x;
  if (i < n) out[i] = c;
}

// fill all tables with -1 + zero the 256B zero page, one dispatch
__global__ __launch_bounds__(256) void init_all_kernel(
    int* __restrict__ tab, long ntab, float* __restrict__ zp){
  long i = (long)blockIdx.x*256 + threadIdx.x;
  if (i < ntab) tab[i] = -1;
  if (blockIdx.x == 0 && threadIdx.x < 64) zp[threadIdx.x] = 0.f;
}

struct BuildArgs {
  const int* im[6];
  const int* om[6];
  int   M[6];
  int   nin[6];
  int   nout[6];
  long  toff[6];   // int offsets into table base
};

// all 6 layers' inverse tables, one dispatch (z = layer, y = offset k)
__global__ __launch_bounds__(256) void build_all_kernel(
    BuildArgs a, int* __restrict__ tb){
  const int L = blockIdx.z, k = blockIdx.y;
  const int M = a.M[L];
  long t = (long)blockIdx.x*256 + threadIdx.x;
  if (t >= M) return;
  int ii = a.im[L][(long)k*M + t];
  int oo = a.om[L][(long)k*M + t];
  if (ii >= 0 && ii < a.nin[L] && oo >= 0 && oo < a.nout[L])
    tb[a.toff[L] + (long)k*a.nout[L] + oo] = ii;
}

// all 5 weight transposes (9,cin,128) fp32 -> (9,128,cin) bf16, one dispatch.
__global__ __launch_bounds__(256) void prep_all_kernel(
    const float* __restrict__ w0, const float* __restrict__ w1,
    const float* __restrict__ w2, const float* __restrict__ w3,
    const float* __restrict__ w4, uint16_t* __restrict__ wb, long total){
  const long wt64 = 9L*128*64, wt128 = 9L*128*128;
  long idx = (long)blockIdx.x*256 + threadIdx.x;
  if (idx >= total) return;
  int L; long r; int cin;
  if (idx < wt64){ L = 0; r = idx; cin = 64; }
  else { long j = idx - wt64; L = 1 + (int)(j / wt128); r = j % wt128; cin = 128; }
  const float* w = (L==0) ? w0 : (L==1) ? w1 : (L==2) ? w2 : (L==3) ? w3 : w4;
  int k = (int)(r / (128*cin));
  int rem = (int)(r % (128*cin));
  int cout = rem / cin, ci = rem % cin;
  wb[idx] = f2bf(w[((long)k*cin + ci)*128 + cout]);
}

// c0 (1->64 ch) via table: thread = row; 9 table reads + 9 cached gathers + FMA.
__global__ __launch_bounds__(256) void c0_tab_kernel(
    const float* __restrict__ feats, const float* __restrict__ w,
    const float* __restrict__ bias, const int* __restrict__ tab,
    uint16_t* __restrict__ out, int n_out){
  __shared__ float w_s[576];
  __shared__ float b_s[64];
  const int tid = threadIdx.x;
  for (int i = tid; i < 576; i += 256) w_s[i] = w[i];
  if (tid < 64) b_s[tid] = bias[tid];
  __syncthreads();
  long r = (long)blockIdx.x*256 + tid;
  if (r >= n_out) return;
  float f[9];
  #pragma unroll
  for (int k = 0; k < 9; k++){
    int gi = tab[(long)k*n_out + r];
    f[k] = (gi >= 0) ? feats[gi] : 0.f;
  }
  uint16_t* dst = out + r*64;
  #pragma unroll
  for (int c0 = 0; c0 < 64; c0 += 16){
    float a[16];
    #pragma unroll
    for (int j = 0; j < 16; j++) a[j] = b_s[c0+j];
    #pragma unroll
    for (int k = 0; k < 9; k++){
      float fk = f[k];
      #pragma unroll
      for (int j = 0; j < 16; j++) a[j] += fk * w_s[k*64 + c0 + j];
    }
    uint4 o0, o1;
    o0.x = pack2(a[0],a[1]);   o0.y = pack2(a[2],a[3]);
    o0.z = pack2(a[4],a[5]);   o0.w = pack2(a[6],a[7]);
    o1.x = pack2(a[8],a[9]);   o1.y = pack2(a[10],a[11]);
    o1.z = pack2(a[12],a[13]); o1.w = pack2(a[14],a[15]);
    *(uint4*)(dst + c0)     = o0;
    *(uint4*)(dst + c0 + 8) = o1;
  }
}

// Flattened-K gathered GEMM, BM=128 x BN=128, BK=64, 512 thr (8 waves 4x2,
// wave tile 32x64), 2 blocks/CU (80KB LDS). A: 3 bufs depth-2; B: 2 bufs
// depth-1. Input always bf16 [n_in][CIN] inside ws at in_off.
// OUTMODE: 0 = fp32 only; 1 = bf16 only; 2 = both.
template<int CIN, int OUTMODE, bool RELU>
__global__ __launch_bounds__(512,4) void mconv4_kernel(
    const char* __restrict__ ws_base, long in_off, long wtb_off, long zp_off,
    const float* __restrict__ bias, const int* __restrict__ tab,
    float* __restrict__ outf, uint16_t* __restrict__ outb, int n_out){
  constexpr int NS = 9*CIN/64;                       // K-steps of 64
  __shared__ __align__(16) uint16_t ab[3][128*64];   // A: 3 x 16KB
  __shared__ __align__(16) uint16_t bb[2][128*64];   // B: 2 x 16KB

  const int tid = threadIdx.x;
  // bijective XCD-chunked swizzle (m204) for gather L2 locality
  const int nwg = gridDim.x, orig = blockIdx.x;
  const int q = nwg >> 3, rr = nwg & 7, xcd = orig & 7, pos = orig >> 3;
  const int wg = (xcd < rr ? xcd*(q+1) : rr*(q+1) + (xcd-rr)*q) + pos;
  const long rb = (long)wg * 128;

  const int r0 = tid >> 3, sg = tid & 7;
  const int ss0 = sg ^ (r0 & 7);       // r1=r0+64 -> same &7 -> same swizzle

  // A gather offsets: ws-relative uint32, zero-page select folded.
  uint32_t offA[2][9];
  #pragma unroll
  for (int kk = 0; kk < 9; ++kk){
    #pragma unroll
    for (int it = 0; it < 2; ++it){
      long row = rb + it*64 + r0;
      int gi = (row < (long)n_out) ? tab[(long)kk*n_out + row] : -1;
      offA[it][kk] = (gi >= 0)
          ? (uint32_t)(in_off + (long)gi*(CIN*2) + ss0*16)
          : (uint32_t)(zp_off + ss0*16);
    }
  }
  const uint32_t offB = (uint32_t)(wtb_off + ((long)r0*CIN + ss0*8)*2);

  const int lane = tid & 63;
  const int wv = tid >> 6;
  const int wr = (wv >> 1) << 5;    // 4 row-waves x 32
  const int wc = (wv & 1) << 6;     // 2 col-waves x 64
  const int l16 = lane & 15, quad = lane >> 4;

  // bias preload; these prologue VMEM ops retire before the first vmcnt(4)
  float bv[4];
  #pragma unroll
  for (int ct = 0; ct < 4; ++ct) bv[ct] = bias[wc + (ct<<4) + l16];

  f32x4 acc[2][4];
  #pragma unroll
  for (int i = 0; i < 2; i++)
    #pragma unroll
    for (int j = 0; j < 4; j++)
      acc[i][j] = (f32x4){0.f,0.f,0.f,0.f};

  auto stage_a = [&](int step, int nb){
    const int kk  = (CIN == 64) ? step : (step >> 1);
    const int c0b = (CIN == 64) ? 0 : ((step & 1) * 128);
    #pragma unroll
    for (int it = 0; it < 2; ++it)
      gload16(ws_base + offA[it][kk] + c0b, &ab[nb][(it*512+tid)*8]);
  };
  auto stage_b = [&](int step, int nb){
    const int kk  = (CIN == 64) ? step : (step >> 1);
    const int c0b = (CIN == 64) ? 0 : ((step & 1) * 128);
    const uint32_t base = offB + (uint32_t)((long)kk*128*CIN*2 + c0b);
    #pragma unroll
    for (int it = 0; it < 2; ++it)
      gload16(ws_base + base + it*(64*CIN*2), &bb[nb][(it*512+tid)*8]);
  };
  auto compute = [&](int na, int nb){
    const uint16_t* A  = &ab[na][0];
    const uint16_t* Bm = &bb[nb][0];
    __builtin_amdgcn_s_setprio(1);
    #pragma unroll
    for (int ch = 0; ch < 2; ++ch){
      // row&7 == l16&7 for every fragment row (wr,wc,u*16 are 0 mod 8)
      const int xs = ((((ch << 2) + quad) ^ (l16 & 7)) << 3);
      bf16x8 af[2], bfr[4];
      #pragma unroll
      for (int u = 0; u < 2; ++u)
        af[u]  = *(const bf16x8*)&A [((wr + (u<<4) + l16) << 6) + xs];
      #pragma unroll
      for (int u = 0; u < 4; ++u)
        bfr[u] = *(const bf16x8*)&Bm[((wc + (u<<4) + l16) << 6) + xs];
      #pragma unroll
      for (int rt = 0; rt < 2; ++rt)
        #pragma unroll
        for (int ct = 0; ct < 4; ++ct)
          acc[rt][ct] = __builtin_amdgcn_mfma_f32_16x16x32_bf16(
              af[rt], bfr[ct], acc[rt][ct], 0, 0, 0);
    }
    __builtin_amdgcn_s_setprio(0);
  };

  // Asymmetric pipeline. Issue order per wave: ... A(t+2) B(t+1) | wait.
  // vmcnt(4) leaves exactly {A(t+2),B(t+1)}; A(t),B(t) and older retired.
  stage_a(0, 0);
  stage_a(1, 1);
  stage_b(0, 0);
  #pragma unroll
  for (int t = 0; t < NS; ++t){
    if (t + 2 < NS) stage_a(t+2, (t+2)%3);
    if (t + 1 < NS) stage_b(t+1, (t+1)&1);
    if (t + 2 < NS){
      asm volatile("s_waitcnt vmcnt(4)" ::: "memory");
    } else if (t + 1 < NS){
      asm volatile("s_waitcnt vmcnt(2)" ::: "memory");
    } else {
      asm volatile("s_waitcnt vmcnt(0)" ::: "memory");
    }
    __builtin_amdgcn_sched_barrier(0);
    __builtin_amdgcn_s_barrier();     // all waves' step-t tiles landed
    compute(t%3, t&1);
    if (t + 1 < NS)
      __builtin_amdgcn_s_barrier();   // WAR: bufs written at t+1 were read <=t
  }

  // C/D mapping (verified): col = l16, row = quad*4 + r
  #pragma unroll
  for (int ct = 0; ct < 4; ++ct){
    const int cout = wc + (ct<<4) + l16;
    #pragma unroll
    for (int rt = 0; rt < 2; ++rt){
      #pragma unroll
      for (int r = 0; r < 4; ++r){
        long row = rb + wr + (rt<<4) + (quad<<2) + r;
        if (row < (long)n_out){
          float v = acc[rt][ct][r] + bv[ct];
          if (RELU) v = v > 0.f ? v : 0.f;
          if constexpr (OUTMODE == 0 || OUTMODE == 2) outf[row*128 + cout] = v;
          if constexpr (OUTMODE == 1 || OUTMODE == 2) outb[row*128 + cout] = f2bf(v);
        }
      }
    }
  }
}

static inline long cdivl(long a, long b){ return (a + b - 1) / b; }

extern "C" void kernel_launch(void* const* d_in, const int* in_sizes, int n_in_args,
                              void* d_out, int out_size, void* d_ws, size_t ws_size,
                              hipStream_t stream) {
  const float* feats = (const float*)d_in[0];
  const float* w_c0 = (const float*)d_in[1];
  const float* b_c0 = (const float*)d_in[2];
  const int* in_c0  = (const int*)d_in[3];
  const int* out_c0 = (const int*)d_in[4];
  const float* w_d0 = (const float*)d_in[5];
  const float* b_d0 = (const float*)d_in[6];
  const int* in_d0  = (const int*)d_in[7];
  const int* out_d0 = (const int*)d_in[8];
  const float* w_c1 = (const float*)d_in[9];
  const float* b_c1 = (const float*)d_in[10];
  const int* in_c1  = (const int*)d_in[11];
  const int* out_c1 = (const int*)d_in[12];
  const float* w_d1 = (const float*)d_in[13];
  const float* b_d1 = (const float*)d_in[14];
  const int* in_d1  = (const int*)d_in[15];
  const int* out_d1 = (const int*)d_in[16];
  const float* w_c2 = (const float*)d_in[17];
  const float* b_c2 = (const float*)d_in[18];
  const int* in_c2  = (const int*)d_in[19];
  const int* out_c2 = (const int*)d_in[20];
  const float* w_d2 = (const float*)d_in[21];
  const float* b_d2 = (const float*)d_in[22];
  const int* in_d2  = (const int*)d_in[23];
  const int* out_d2 = (const int*)d_in[24];

  const int n0   = in_sizes[0];
  const int M_c0 = in_sizes[3]  / 9;
  const int M_d0 = in_sizes[7]  / 9;
  const int M_c1 = in_sizes[11] / 9;
  const int M_d1 = in_sizes[15] / 9;
  const int M_c2 = in_sizes[19] / 9;
  const int M_d2 = in_sizes[23] / 9;
  const int n1   = M_c1;
  const int n2   = M_c2;
  const int n3   = out_size/128 - n1 - n2;

  bool sane = n0 > 0 && out_size % 128 == 0 &&
              M_c0 > 0 && M_d0 > 0 && M_d1 > 0 && M_d2 > 0 &&
              n1 > 0 && n2 > 0 && n3 > 0;

  long maxElems = (long)n0*64;
  if ((long)n1*128 > maxElems) maxElems = (long)n1*128;
  if ((long)n2*128 > maxElems) maxElems = (long)n2*128;
  long fbytes = (maxElems*2 + 255)/256*256;
  long ntab   = sane ? 9L*((long)n0 + 2L*n1 + 2L*n2 + n3) : 0;
  long tbytes = (ntab*4 + 255)/256*256;
  long wt64  = 9L*128*64, wt128 = 9L*128*128;
  long wbytes = ((wt64 + 4*wt128)*2 + 255)/256*256;
  long zbytes = 256;
  long b1bytes = sane ? ((long)n2*128*2 + 255)/256*256 : 0;
  long b0bytes = sane ? ((long)n1*128*2 + 255)/256*256 : 0;
  long need_full = fbytes + tbytes + wbytes + zbytes + 256 + b1bytes + b0bytes;

  if (!sane || ws_size < (size_t)need_full){
    float C = (float)(16 + (int)std::min<size_t>(ws_size >> 20, (size_t)100000));
    if (!sane) C *= 1099511627776.0f;
    diag_kernel<<<cdivl(out_size,256),256,0,stream>>>((float*)d_out, out_size, C);
    return;
  }

  // ws: [ fbuf | tables x6 | wtb x5 | zero page | bf1 | bf0 ]
  uint16_t* fbuf = (uint16_t*)d_ws;
  long tab_off    = fbytes;
  long wtb_off    = fbytes + tbytes;
  long zp_off     = fbytes + tbytes + wbytes;
  long bf1_off    = zp_off + zbytes + 256;
  long bf0_off    = bf1_off + b1bytes;
  const char* wsb = (const char*)d_ws;
  int* tb        = (int*)((char*)d_ws + tab_off);
  float* zp_p    = (float*)((char*)d_ws + zp_off);
  uint16_t* bf1  = (uint16_t*)((char*)d_ws + bf1_off);
  uint16_t* bf0  = (uint16_t*)((char*)d_ws + bf0_off);

  // table int offsets (contiguous, order: c0 d0 c1 d1 c2 d2)
  long t_c0 = 0;
  long t_d0 = t_c0 + 9L*n0;
  long t_c1 = t_d0 + 9L*n1;
  long t_d1 = t_c1 + 9L*n1;
  long t_c2 = t_d1 + 9L*n2;
  long t_d2 = t_c2 + 9L*n2;

  float* out2 = (float*)d_out;
  float* out1 = out2 + (long)n3*128;
  float* out0 = out1 + (long)n2*128;

  // 1) init all tables + zero page
  init_all_kernel<<<cdivl(ntab,256),256,0,stream>>>(tb, ntab, zp_p);

  // 2) build all 6 tables
  BuildArgs ba;
  ba.im[0]=in_c0;  ba.om[0]=out_c0; ba.M[0]=M_c0; ba.nin[0]=n0; ba.nout[0]=n0; ba.toff[0]=t_c0;
  ba.im[1]=in_d0;  ba.om[1]=out_d0; ba.M[1]=M_d0; ba.nin[1]=n0; ba.nout[1]=n1; ba.toff[1]=t_d0;
  ba.im[2]=in_c1;  ba.om[2]=out_c1; ba.M[2]=M_c1; ba.nin[2]=n1; ba.nout[2]=n1; ba.toff[2]=t_c1;
  ba.im[3]=in_d1;  ba.om[3]=out_d1; ba.M[3]=M_d1; ba.nin[3]=n1; ba.nout[3]=n2; ba.toff[3]=t_d1;
  ba.im[4]=in_c2;  ba.om[4]=out_c2; ba.M[4]=M_c2; ba.nin[4]=n2; ba.nout[4]=n2; ba.toff[4]=t_c2;
  ba.im[5]=in_d2;  ba.om[5]=out_d2; ba.M[5]=M_d2; ba.nin[5]=n2; ba.nout[5]=n3; ba.toff[5]=t_d2;
  long maxM = M_c0;
  for (int i = 0; i < 6; ++i) if (ba.M[i] > maxM) maxM = ba.M[i];
  dim3 bg((unsigned)cdivl(maxM,256), 9, 6);
  build_all_kernel<<<bg,256,0,stream>>>(ba, tb);

  // 3) all weight transposes
  long wtotal = wt64 + 4*wt128;
  prep_all_kernel<<<cdivl(wtotal,256),256,0,stream>>>(
      w_d0, w_c1, w_d1, w_c2, w_d2,
      (uint16_t*)((char*)d_ws + wtb_off), wtotal);

  // 4) c0: feats fp32 -> fbuf(x) bf16 [n0][64]
  c0_tab_kernel<<<cdivl(n0,256),256,0,stream>>>(feats, w_c0, b_c0, tb + t_c0, fbuf, n0);

  // 5) d0: x bf16 -> out0 fp32 + bf0 bf16, relu
  mconv4_kernel<64,2,true><<<cdivl(n1,128),512,0,stream>>>(
      wsb, 0L, wtb_off, zp_off, b_d0, tb + t_d0, out0, bf0, n1);

  // 6) c1: bf0 bf16 -> fbuf(y) bf16
  mconv4_kernel<128,1,false><<<cdivl(n1,128),512,0,stream>>>(
      wsb, bf0_off, wtb_off + wt64*2, zp_off, b_c1, tb + t_c1, nullptr, fbuf, n1);

  // 7) d1: y bf16 -> out1 fp32 + bf1 bf16, relu
  mconv4_kernel<128,2,true><<<cdivl(n2,128),512,0,stream>>>(
      wsb, 0L, wtb_off + (wt64 + wt128)*2, zp_off, b_d1, tb + t_d1, out1, bf1, n2);

  // 8) c2: bf1 bf16 -> fbuf(z) bf16
  mconv4_kernel<128,1,false><<<cdivl(n2,128),512,0,stream>>>(
      wsb, bf1_off, wtb_off + (wt64 + 2*wt128)*2, zp_off, b_c2, tb + t_c2, nullptr, fbuf, n2);

  // 9) d2: z bf16 -> out2 fp32
  mconv4_kernel<128,0,false><<<cdivl(n3,128),512,0,stream>>>(
      wsb, 0L, wtb_off + (wt64 + 3*wt128)*2, zp_off, b_d2, tb + t_d2, out2, nullptr, n3);
}